// Round 18
// baseline (152.296 us; speedup 1.0000x reference)
//
#include <hip/hip_runtime.h>
#include <stdint.h>

typedef float  f32x4 __attribute__((ext_vector_type(4)));
typedef int    i32x4 __attribute__((ext_vector_type(4)));
typedef short  bf16x8 __attribute__((ext_vector_type(8)));
typedef unsigned short u16;
typedef unsigned int   u32;

#define DEVINL __device__ __forceinline__

// fp32 -> bf16 RNE
DEVINL u16 f2bf(float f) {
  u32 u = __builtin_bit_cast(u32, f);
  u32 r = u + 0x7fffu + ((u >> 16) & 1u);
  return (u16)(r >> 16);
}

// packed fp32x2 -> bf16x2
DEVINL u32 cvtpk(float lo, float hi) {
  u32 r;
  asm("v_cvt_pk_bf16_f32 %0, %1, %2" : "=v"(r) : "v"(lo), "v"(hi));
  return r;
}

// D += A*B  (16x16x32 bf16 MFMA)
DEVINL void mfma16(f32x4& d, i32x4 a, i32x4 b) {
  d = __builtin_amdgcn_mfma_f32_16x16x32_bf16(
      __builtin_bit_cast(bf16x8, a), __builtin_bit_cast(bf16x8, b), d, 0, 0, 0);
}

// async global->LDS, 16B per lane; LDS dest linear per wave (base + lane*16)
#define GLD16(gp, lp) __builtin_amdgcn_global_load_lds( \
    (__attribute__((address_space(1))) void*)(gp), \
    (__attribute__((address_space(3))) void*)(lp), 16, 0, 0)

// one launch converting all three fp32 arrays to bf16
__global__ void cvt3_f32_bf16(const float* __restrict__ s0, u16* __restrict__ d0, int n0,
                              const float* __restrict__ s1, u16* __restrict__ d1, int n1,
                              const float* __restrict__ s2, u16* __restrict__ d2, int n2) {
  int i = blockIdx.x * blockDim.x + threadIdx.x;
  int stride = gridDim.x * blockDim.x;
  int nt = n0 + n1 + n2;
  for (; i < nt; i += stride) {
    const float* s; u16* d; int j = i;
    if (j < n0) { s = s0; d = d0; }
    else if ((j -= n0) < n1) { s = s1; d = d1; }
    else { j -= n1; s = s2; d = d2; }
    float4 v = ((const float4*)s)[j];
    ushort4 o;
    o.x = f2bf(v.x); o.y = f2bf(v.y); o.z = f2bf(v.z); o.w = f2bf(v.w);
    ((ushort4*)d)[j] = o;
  }
}

// ---------------------------------------------------------------------------
// C = A * B^T (+bias). BK=64 dbuf 2-phase, N-major XCD walk. 512 threads =
// 8 waves (2x4 grid): doubles waves/CU on a latency-bound kernel (same tile,
// same staging bytes, same barrier count — only intra-block TLP changes;
// the lever that won attn r17).
// EPI==0: fp32 C + bias via LDS-retile.  EPI==1: QKV scatter via LDS-retile.
// ---------------------------------------------------------------------------
template<int BM, int BN, int FM, int FN, int EPI>
__global__ __launch_bounds__(512) void gemm_bt(
    const u16* __restrict__ A, const u16* __restrict__ Bw,
    int M, int N, const float* __restrict__ bias,
    float* __restrict__ Cf, u16* __restrict__ Qb, u16* __restrict__ Kb, u16* __restrict__ Vtb)
{
  constexpr int BK = 64;
  constexpr int K  = 768;
  constexpr int T  = K / BK;            // 12
  constexpr int ABYT = BM * BK * 2;
  constexpr int BBYT = BN * BK * 2;
  __shared__ __align__(16) unsigned char sm[2 * (ABYT + BBYT)];

  const int tid = threadIdx.x;
  const int l   = tid & 63;
  const int wid = tid >> 6;             // 0..7
  const int wm  = wid >> 2, wn = wid & 3;   // 2 x 4 wave grid
  const int g4  = l >> 4;
  const int c15 = l & 15;

  const int ntiles = N / BN;
  const int mt_x = (M / BM) >> 3;       // m-tiles per XCD chunk
  const int xcd  = (int)blockIdx.x & 7;
  const int seq  = (int)blockIdx.x >> 3;
  const int mbase = (xcd * mt_x + (seq % mt_x)) * BM;
  const int nbase = (seq / mt_x) * BN;

  auto stage = [&](int buf, int kt) {
    unsigned char* ab = sm + buf * (ABYT + BBYT);
    unsigned char* bb = ab + ABYT;
    // plane-major [8 planes][ROWS][16B]; 512 threads
    #pragma unroll
    for (int c = 0; c < BM / 64; ++c) {
      int ch = c * 512 + tid;
      int row = ch & (BM - 1), pl = ch / BM;
      GLD16(A + (size_t)(mbase + row) * K + kt * BK + pl * 8, ab + ch * 16);
    }
    #pragma unroll
    for (int c = 0; c < BN / 64; ++c) {
      int ch = c * 512 + tid;
      int row = ch & (BN - 1), pl = ch / BN;
      GLD16(Bw + (size_t)(nbase + row) * K + kt * BK + pl * 8, bb + ch * 16);
    }
  };

  f32x4 acc[FM][FN] = {};

  stage(0, 0);
  __syncthreads();

  for (int kt = 0; kt < T; ++kt) {
    int cur = kt & 1;
    if (kt + 1 < T) stage(cur ^ 1, kt + 1);
    unsigned char* ab = sm + cur * (ABYT + BBYT);
    unsigned char* bb = ab + ABYT;
    i32x4 af[FM][2], bf[FN][2];
    #pragma unroll
    for (int mt = 0; mt < FM; ++mt)
      #pragma unroll
      for (int ks = 0; ks < 2; ++ks) {
        int row = wm * (BM / 2) + mt * 16 + c15;
        af[mt][ks] = *(const i32x4*)(ab + ((ks * 4 + g4) * BM + row) * 16);
      }
    #pragma unroll
    for (int nt = 0; nt < FN; ++nt)
      #pragma unroll
      for (int ks = 0; ks < 2; ++ks) {
        int row = wn * (BN / 4) + nt * 16 + c15;
        bf[nt][ks] = *(const i32x4*)(bb + ((ks * 4 + g4) * BN + row) * 16);
      }
    __builtin_amdgcn_s_setprio(1);
    #pragma unroll
    for (int mt = 0; mt < FM; ++mt)
      #pragma unroll
      for (int nt = 0; nt < FN; ++nt)
        #pragma unroll
        for (int ks = 0; ks < 2; ++ks)
          mfma16(acc[mt][nt], af[mt][ks], bf[nt][ks]);
    __builtin_amdgcn_s_setprio(0);
    __syncthreads();
  }

  if constexpr (EPI == 0) {
    // ---- LDS-retile fp32 epilogue ----
    unsigned char* L = sm;
    #pragma unroll
    for (int nt = 0; nt < FN; ++nt) {
      int nrel = wn * (BN / 4) + nt * 16 + c15;
      float bv = bias[nbase + nrel];
      #pragma unroll
      for (int mt = 0; mt < FM; ++mt) {
        int m0 = wm * (BM / 2) + mt * 16 + g4 * 4;
        #pragma unroll
        for (int j = 0; j < 4; ++j) {
          int m = m0 + j;
          *(float*)(L + m * (BN * 4) + ((nrel * 4) ^ ((m & 7) << 4))) =
              acc[mt][nt][j] + bv;
        }
      }
    }
    __syncthreads();

    constexpr int CPR = BN / 4;           // 16B chunks per row
    #pragma unroll
    for (int k = 0; k < (BM * CPR) / 512; ++k) {
      int chunk = k * 512 + tid;
      int row = chunk / CPR, c = chunk % CPR;
      i32x4 vdat = *(const i32x4*)(L + row * (BN * 4) + ((c * 16) ^ ((row & 7) << 4)));
      *(i32x4*)(Cf + (size_t)(mbase + row) * N + nbase + c * 4) = vdat;
    }
  } else {
    // ---- LDS-retile epilogue (coalesced 128B+ runs) ----
    const int which = nbase / 768;
    const int hbase = (nbase - which * 768) >> 6;
    unsigned char* L = sm;

    if (which < 2) {
      const float sc = (which == 0) ? 0.125f : 1.0f;
      #pragma unroll
      for (int nt = 0; nt < FN; ++nt) {
        int nrel = wn * (BN / 4) + nt * 16 + c15;
        float bv = bias[nbase + nrel];
        #pragma unroll
        for (int mt = 0; mt < FM; ++mt) {
          int m0 = wm * (BM / 2) + mt * 16 + g4 * 4;
          #pragma unroll
          for (int j = 0; j < 4; ++j) {
            int m = m0 + j;
            *(u16*)(L + m * 256 + ((nrel * 2) ^ ((m & 7) << 4))) =
                f2bf((acc[mt][nt][j] + bv) * sc);
          }
        }
      }
    } else {
      #pragma unroll
      for (int nt = 0; nt < FN; ++nt) {
        int nrel = wn * (BN / 4) + nt * 16 + c15;
        float bv = bias[nbase + nrel];
        #pragma unroll
        for (int mt = 0; mt < FM; ++mt) {
          int m0 = wm * (BM / 2) + mt * 16 + g4 * 4;
          uint2 uu;
          uu.x = cvtpk(acc[mt][nt][0] + bv, acc[mt][nt][1] + bv);
          uu.y = cvtpk(acc[mt][nt][2] + bv, acc[mt][nt][3] + bv);
          *(uint2*)(L + nrel * 256 + ((m0 * 2) ^ ((nrel & 7) << 4))) = uu;
        }
      }
    }
    __syncthreads();

    const int b  = mbase >> 10;
    const int pb = mbase & 1023;
    #pragma unroll
    for (int k = 0; k < 4; ++k) {
      int chunk = k * 512 + tid;
      int row = chunk >> 4, c = chunk & 15;
      i32x4 vdat = *(const i32x4*)(L + row * 256 + ((c * 16) ^ ((row & 7) << 4)));
      if (which < 2) {
        int h = hbase + (c >> 3), d0 = (c & 7) * 8;
        int bh = b * 12 + h;
        u16* base = (which == 0) ? Qb : Kb;
        *(i32x4*)(base + ((size_t)bh * 1024 + pb + row) * 64 + d0) = vdat;
      } else {
        int h = hbase + (row >> 6), d = row & 63;
        int bh = b * 12 + h;
        *(i32x4*)(Vtb + ((size_t)bh * 64 + d) * 1024 + pb + c * 8) = vdat;
      }
    }
  }
}

// ---------------------------------------------------------------------------
// Flash attention — 8 waves x 16 q-rows (512 thr), fixed-shift softmax
// (round-17 structure, unchanged — the session's attn winner).
// ---------------------------------------------------------------------------
__global__ __launch_bounds__(512) void attn_fwd(
    const u16* __restrict__ Qb, const u16* __restrict__ Kb,
    const u16* __restrict__ Vtb, u16* __restrict__ Ob)
{
  __shared__ __align__(16) unsigned char sm[16384 + 4 * 8192];
  const int tid = threadIdx.x;
  const int l = tid & 63, wid = tid >> 6;
  const int g4 = l >> 4, c15 = l & 15;
  const int bid = blockIdx.x;
  const int bh = bid % 96, qt = bid / 96;

  const size_t bhoff = (size_t)bh * (1024 * 64);
  const u16* Qg = Qb + bhoff + (size_t)qt * 128 * 64;
  const u16* Kg = Kb + bhoff;
  const u16* Vg = Vtb + bhoff;

  #pragma unroll
  for (int c = 0; c < 2; ++c) {
    int ch = c * 512 + tid;
    int row = ch & 127, pl = ch >> 7;
    GLD16(Qg + (size_t)row * 64 + pl * 8, sm + ch * 16);
  }

  auto stageKV = [&](int buf, int t) {
    unsigned char* kb_ = sm + 16384 + buf * 8192;
    unsigned char* vb_ = sm + 32768 + buf * 8192;
    int row = tid & 63, pl = (tid >> 6) & 7;
    GLD16(Kg + (size_t)(t * 64 + row) * 64 + pl * 8, kb_ + tid * 16);
    GLD16(Vg + (size_t)row * 1024 + t * 64 + pl * 8, vb_ + tid * 16);
  };

  stageKV(0, 0);
  __syncthreads();

  i32x4 qf[2];
  #pragma unroll
  for (int ks = 0; ks < 2; ++ks) {
    int row = wid * 16 + c15;
    qf[ks] = *(const i32x4*)(sm + ((ks * 4 + g4) * 128 + row) * 16);
  }
  __syncthreads();

  unsigned char* pw = sm + wid * 2048;

  const i32x4 ones = {0x3F803F80, 0x3F803F80, 0x3F803F80, 0x3F803F80};
  constexpr float LOG2E = 1.44269504f;
  constexpr float SHIFT2 = -4.0f * LOG2E;

  f32x4 ot[4] = {};
  f32x4 lacc = {};

  for (int t = 0; t < 16; ++t) {
    int cur = t & 1;
    if (t + 1 < 16) stageKV(cur ^ 1, t + 1);
    unsigned char* kb_ = sm + 16384 + cur * 8192;
    unsigned char* vb_ = sm + 32768 + cur * 8192;

    f32x4 st[4] = {};
    __builtin_amdgcn_s_setprio(1);
    #pragma unroll
    for (int ks = 0; ks < 2; ++ks)
      #pragma unroll
      for (int kmt = 0; kmt < 4; ++kmt) {
        i32x4 ka = *(const i32x4*)(kb_ + ((ks * 4 + g4) * 64 + kmt * 16 + c15) * 16);
        mfma16(st[kmt], ka, qf[ks]);
      }
    __builtin_amdgcn_s_setprio(0);

    #pragma unroll
    for (int kmt = 0; kmt < 4; ++kmt) {
      float p0 = exp2f(__builtin_fmaf(st[kmt][0], LOG2E, SHIFT2));
      float p1 = exp2f(__builtin_fmaf(st[kmt][1], LOG2E, SHIFT2));
      float p2 = exp2f(__builtin_fmaf(st[kmt][2], LOG2E, SHIFT2));
      float p3 = exp2f(__builtin_fmaf(st[kmt][3], LOG2E, SHIFT2));
      int k0 = kmt * 16 + 4 * g4;
      uint2 ww;
      ww.x = cvtpk(p0, p1);
      ww.y = cvtpk(p2, p3);
      *(uint2*)(pw + ((k0 >> 3) * 16 + c15) * 16 + (k0 & 7) * 2) = ww;
    }

    i32x4 pb[2];
    #pragma unroll
    for (int ks = 0; ks < 2; ++ks)
      pb[ks] = *(const i32x4*)(pw + ((ks * 4 + g4) * 16 + c15) * 16);

    __builtin_amdgcn_s_setprio(1);
    #pragma unroll
    for (int ks = 0; ks < 2; ++ks) {
      #pragma unroll
      for (int dmt = 0; dmt < 4; ++dmt) {
        i32x4 va = *(const i32x4*)(vb_ + ((ks * 4 + g4) * 64 + dmt * 16 + c15) * 16);
        mfma16(ot[dmt], va, pb[ks]);
      }
      mfma16(lacc, ones, pb[ks]);
    }
    __builtin_amdgcn_s_setprio(0);
    __syncthreads();
  }

  const int b = bh / 12, h = bh % 12;
  float inv = 1.0f / lacc[0];
  int q = qt * 128 + wid * 16 + c15;
  size_t rowoff = ((size_t)(b * 1024 + q) * 12 + h) * 64;
  #pragma unroll
  for (int dmt = 0; dmt < 4; ++dmt) {
    int d0 = dmt * 16 + g4 * 4;
    uint2 uu;
    uu.x = cvtpk(ot[dmt][0] * inv, ot[dmt][1] * inv);
    uu.y = cvtpk(ot[dmt][2] * inv, ot[dmt][3] * inv);
    *(uint2*)(Ob + rowoff + d0) = uu;
  }
}

extern "C" void kernel_launch(void* const* d_in, const int* in_sizes, int n_in,
                              void* d_out, int out_size, void* d_ws, size_t ws_size,
                              hipStream_t stream) {
  const float* x    = (const float*)d_in[0];
  const float* qkvw = (const float*)d_in[1];
  const float* qkvb = (const float*)d_in[2];
  const float* outw = (const float*)d_in[3];
  const float* outb = (const float*)d_in[4];
  float* out = (float*)d_out;

  unsigned char* ws = (unsigned char*)d_ws;
  u16* xb  = (u16*)(ws);                          // 12.58 MB  [8192][768] bf16
  u16* wqb = (u16*)(ws + 12582912);               //  3.54 MB  [2304][768] bf16
  u16* wob = (u16*)(ws + 16121856);               //  1.18 MB  [768][768]  bf16
  u16* Qbf = (u16*)(ws + 17301504);               // 12.58 MB  [96][1024][64]
  u16* Kbf = (u16*)(ws + 29884416);               // 12.58 MB  [96][1024][64]
  u16* Vtb = (u16*)(ws + 42467328);               // 12.58 MB  [96][64][1024]
  u16* Ob  = xb;                                  // reuse x region (dead after gemm1)

  cvt3_f32_bf16<<<dim3(2048), dim3(256), 0, stream>>>(
      x, xb, 8192 * 768 / 4, qkvw, wqb, 2304 * 768 / 4, outw, wob, 768 * 768 / 4);

  gemm_bt<128, 128, 4, 2, 1><<<dim3(1152), dim3(512), 0, stream>>>(
      xb, wqb, 8192, 2304, qkvb, nullptr, Qbf, Kbf, Vtb);

  attn_fwd<<<dim3(768), dim3(512), 0, stream>>>(Qbf, Kbf, Vtb, Ob);

  gemm_bt<128, 64, 4, 1, 0><<<dim3(768), dim3(512), 0, stream>>>(
      Ob, wob, 8192, 768, outb, out, nullptr, nullptr, nullptr);
}

// Round 19
// 149.530 us; speedup vs baseline: 1.0185x; 1.0185x over previous
//
#include <hip/hip_runtime.h>
#include <stdint.h>

typedef float  f32x4 __attribute__((ext_vector_type(4)));
typedef int    i32x4 __attribute__((ext_vector_type(4)));
typedef short  bf16x8 __attribute__((ext_vector_type(8)));
typedef unsigned short u16;
typedef unsigned int   u32;

#define DEVINL __device__ __forceinline__

// fp32 -> bf16 RNE
DEVINL u16 f2bf(float f) {
  u32 u = __builtin_bit_cast(u32, f);
  u32 r = u + 0x7fffu + ((u >> 16) & 1u);
  return (u16)(r >> 16);
}

// packed fp32x2 -> bf16x2
DEVINL u32 cvtpk(float lo, float hi) {
  u32 r;
  asm("v_cvt_pk_bf16_f32 %0, %1, %2" : "=v"(r) : "v"(lo), "v"(hi));
  return r;
}

// D += A*B  (16x16x32 bf16 MFMA)
DEVINL void mfma16(f32x4& d, i32x4 a, i32x4 b) {
  d = __builtin_amdgcn_mfma_f32_16x16x32_bf16(
      __builtin_bit_cast(bf16x8, a), __builtin_bit_cast(bf16x8, b), d, 0, 0, 0);
}

// async global->LDS, 16B per lane; LDS dest linear per wave (base + lane*16)
#define GLD16(gp, lp) __builtin_amdgcn_global_load_lds( \
    (__attribute__((address_space(1))) void*)(gp), \
    (__attribute__((address_space(3))) void*)(lp), 16, 0, 0)

// one launch converting all three fp32 arrays to bf16
__global__ void cvt3_f32_bf16(const float* __restrict__ s0, u16* __restrict__ d0, int n0,
                              const float* __restrict__ s1, u16* __restrict__ d1, int n1,
                              const float* __restrict__ s2, u16* __restrict__ d2, int n2) {
  int i = blockIdx.x * blockDim.x + threadIdx.x;
  int stride = gridDim.x * blockDim.x;
  int nt = n0 + n1 + n2;
  for (; i < nt; i += stride) {
    const float* s; u16* d; int j = i;
    if (j < n0) { s = s0; d = d0; }
    else if ((j -= n0) < n1) { s = s1; d = d1; }
    else { j -= n1; s = s2; d = d2; }
    float4 v = ((const float4*)s)[j];
    ushort4 o;
    o.x = f2bf(v.x); o.y = f2bf(v.y); o.z = f2bf(v.z); o.w = f2bf(v.w);
    ((ushort4*)d)[j] = o;
  }
}

// ---------------------------------------------------------------------------
// C = A * B^T (+bias). BK=64 double-buffered 2-phase, N-major XCD walk
// (round-15/17 structure — measured best: gemm1 70.6-70.9us, FETCH 22.6MB).
// 256 threads / 4 waves: r18 proved intra-block TLP is null for this
// barrier-synced loop (occupancy 2x, time unchanged) — per-block load-latency
// critical path is the limiter; 4-wave blocks minimize VGPR+LDS footprint.
// EPI==0: fp32 C + bias via LDS-retile.  EPI==1: QKV scatter via LDS-retile.
// ---------------------------------------------------------------------------
template<int BM, int BN, int FM, int FN, int EPI>
__global__ __launch_bounds__(256) void gemm_bt(
    const u16* __restrict__ A, const u16* __restrict__ Bw,
    int M, int N, const float* __restrict__ bias,
    float* __restrict__ Cf, u16* __restrict__ Qb, u16* __restrict__ Kb, u16* __restrict__ Vtb)
{
  constexpr int BK = 64;
  constexpr int K  = 768;
  constexpr int T  = K / BK;            // 12
  constexpr int ABYT = BM * BK * 2;
  constexpr int BBYT = BN * BK * 2;
  __shared__ __align__(16) unsigned char sm[2 * (ABYT + BBYT)];

  const int tid = threadIdx.x;
  const int l   = tid & 63;
  const int wid = tid >> 6;
  const int wm  = wid >> 1, wn = wid & 1;
  const int g4  = l >> 4;
  const int c15 = l & 15;

  const int ntiles = N / BN;
  const int mt_x = (M / BM) >> 3;       // m-tiles per XCD chunk
  const int xcd  = (int)blockIdx.x & 7;
  const int seq  = (int)blockIdx.x >> 3;
  const int mbase = (xcd * mt_x + (seq % mt_x)) * BM;
  const int nbase = (seq / mt_x) * BN;

  auto stage = [&](int buf, int kt) {
    unsigned char* ab = sm + buf * (ABYT + BBYT);
    unsigned char* bb = ab + ABYT;
    #pragma unroll
    for (int c = 0; c < BM / 32; ++c) {
      int ch = c * 256 + tid;
      int row = ch & (BM - 1), pl = ch / BM;
      GLD16(A + (size_t)(mbase + row) * K + kt * BK + pl * 8, ab + ch * 16);
    }
    #pragma unroll
    for (int c = 0; c < BN / 32; ++c) {
      int ch = c * 256 + tid;
      int row = ch & (BN - 1), pl = ch / BN;
      GLD16(Bw + (size_t)(nbase + row) * K + kt * BK + pl * 8, bb + ch * 16);
    }
  };

  f32x4 acc[FM][FN] = {};

  stage(0, 0);
  __syncthreads();

  for (int kt = 0; kt < T; ++kt) {
    int cur = kt & 1;
    if (kt + 1 < T) stage(cur ^ 1, kt + 1);
    unsigned char* ab = sm + cur * (ABYT + BBYT);
    unsigned char* bb = ab + ABYT;
    i32x4 af[FM][2], bf[FN][2];
    #pragma unroll
    for (int mt = 0; mt < FM; ++mt)
      #pragma unroll
      for (int ks = 0; ks < 2; ++ks) {
        int row = wm * (BM / 2) + mt * 16 + c15;
        af[mt][ks] = *(const i32x4*)(ab + ((ks * 4 + g4) * BM + row) * 16);
      }
    #pragma unroll
    for (int nt = 0; nt < FN; ++nt)
      #pragma unroll
      for (int ks = 0; ks < 2; ++ks) {
        int row = wn * (BN / 2) + nt * 16 + c15;
        bf[nt][ks] = *(const i32x4*)(bb + ((ks * 4 + g4) * BN + row) * 16);
      }
    __builtin_amdgcn_s_setprio(1);
    #pragma unroll
    for (int mt = 0; mt < FM; ++mt)
      #pragma unroll
      for (int nt = 0; nt < FN; ++nt)
        #pragma unroll
        for (int ks = 0; ks < 2; ++ks)
          mfma16(acc[mt][nt], af[mt][ks], bf[nt][ks]);
    __builtin_amdgcn_s_setprio(0);
    __syncthreads();
  }

  if constexpr (EPI == 0) {
    // ---- LDS-retile fp32 epilogue ----
    unsigned char* L = sm;
    #pragma unroll
    for (int nt = 0; nt < FN; ++nt) {
      int nrel = wn * (BN / 2) + nt * 16 + c15;
      float bv = bias[nbase + nrel];
      #pragma unroll
      for (int mt = 0; mt < FM; ++mt) {
        int m0 = wm * (BM / 2) + mt * 16 + g4 * 4;
        #pragma unroll
        for (int j = 0; j < 4; ++j) {
          int m = m0 + j;
          *(float*)(L + m * (BN * 4) + ((nrel * 4) ^ ((m & 7) << 4))) =
              acc[mt][nt][j] + bv;
        }
      }
    }
    __syncthreads();

    constexpr int CPR = BN / 4;
    #pragma unroll
    for (int k = 0; k < (BM * CPR) / 256; ++k) {
      int chunk = k * 256 + tid;
      int row = chunk / CPR, c = chunk % CPR;
      i32x4 vdat = *(const i32x4*)(L + row * (BN * 4) + ((c * 16) ^ ((row & 7) << 4)));
      *(i32x4*)(Cf + (size_t)(mbase + row) * N + nbase + c * 4) = vdat;
    }
  } else {
    // ---- LDS-retile epilogue (coalesced 128B+ runs) ----
    const int which = nbase / 768;
    const int hbase = (nbase - which * 768) >> 6;
    unsigned char* L = sm;

    if (which < 2) {
      const float sc = (which == 0) ? 0.125f : 1.0f;
      #pragma unroll
      for (int nt = 0; nt < FN; ++nt) {
        int nrel = wn * (BN / 2) + nt * 16 + c15;
        float bv = bias[nbase + nrel];
        #pragma unroll
        for (int mt = 0; mt < FM; ++mt) {
          int m0 = wm * (BM / 2) + mt * 16 + g4 * 4;
          #pragma unroll
          for (int j = 0; j < 4; ++j) {
            int m = m0 + j;
            *(u16*)(L + m * 256 + ((nrel * 2) ^ ((m & 7) << 4))) =
                f2bf((acc[mt][nt][j] + bv) * sc);
          }
        }
      }
    } else {
      #pragma unroll
      for (int nt = 0; nt < FN; ++nt) {
        int nrel = wn * (BN / 2) + nt * 16 + c15;
        float bv = bias[nbase + nrel];
        #pragma unroll
        for (int mt = 0; mt < FM; ++mt) {
          int m0 = wm * (BM / 2) + mt * 16 + g4 * 4;
          uint2 uu;
          uu.x = cvtpk(acc[mt][nt][0] + bv, acc[mt][nt][1] + bv);
          uu.y = cvtpk(acc[mt][nt][2] + bv, acc[mt][nt][3] + bv);
          *(uint2*)(L + nrel * 256 + ((m0 * 2) ^ ((nrel & 7) << 4))) = uu;
        }
      }
    }
    __syncthreads();

    const int b  = mbase >> 10;
    const int pb = mbase & 1023;
    #pragma unroll
    for (int k = 0; k < 8; ++k) {
      int chunk = k * 256 + tid;
      int row = chunk >> 4, c = chunk & 15;
      i32x4 vdat = *(const i32x4*)(L + row * 256 + ((c * 16) ^ ((row & 7) << 4)));
      if (which < 2) {
        int h = hbase + (c >> 3), d0 = (c & 7) * 8;
        int bh = b * 12 + h;
        u16* base = (which == 0) ? Qb : Kb;
        *(i32x4*)(base + ((size_t)bh * 1024 + pb + row) * 64 + d0) = vdat;
      } else {
        int h = hbase + (row >> 6), d = row & 63;
        int bh = b * 12 + h;
        *(i32x4*)(Vtb + ((size_t)bh * 64 + d) * 1024 + pb + c * 8) = vdat;
      }
    }
  }
}

// ---------------------------------------------------------------------------
// Flash attention — 8 waves x 16 q-rows (512 thr), fixed-shift softmax
// (round-17 structure — the session's attn winner, 24 waves/CU).
// ---------------------------------------------------------------------------
__global__ __launch_bounds__(512) void attn_fwd(
    const u16* __restrict__ Qb, const u16* __restrict__ Kb,
    const u16* __restrict__ Vtb, u16* __restrict__ Ob)
{
  __shared__ __align__(16) unsigned char sm[16384 + 4 * 8192];
  const int tid = threadIdx.x;
  const int l = tid & 63, wid = tid >> 6;
  const int g4 = l >> 4, c15 = l & 15;
  const int bid = blockIdx.x;
  const int bh = bid % 96, qt = bid / 96;

  const size_t bhoff = (size_t)bh * (1024 * 64);
  const u16* Qg = Qb + bhoff + (size_t)qt * 128 * 64;
  const u16* Kg = Kb + bhoff;
  const u16* Vg = Vtb + bhoff;

  #pragma unroll
  for (int c = 0; c < 2; ++c) {
    int ch = c * 512 + tid;
    int row = ch & 127, pl = ch >> 7;
    GLD16(Qg + (size_t)row * 64 + pl * 8, sm + ch * 16);
  }

  auto stageKV = [&](int buf, int t) {
    unsigned char* kb_ = sm + 16384 + buf * 8192;
    unsigned char* vb_ = sm + 32768 + buf * 8192;
    int row = tid & 63, pl = (tid >> 6) & 7;
    GLD16(Kg + (size_t)(t * 64 + row) * 64 + pl * 8, kb_ + tid * 16);
    GLD16(Vg + (size_t)row * 1024 + t * 64 + pl * 8, vb_ + tid * 16);
  };

  stageKV(0, 0);
  __syncthreads();

  i32x4 qf[2];
  #pragma unroll
  for (int ks = 0; ks < 2; ++ks) {
    int row = wid * 16 + c15;
    qf[ks] = *(const i32x4*)(sm + ((ks * 4 + g4) * 128 + row) * 16);
  }
  __syncthreads();

  unsigned char* pw = sm + wid * 2048;

  const i32x4 ones = {0x3F803F80, 0x3F803F80, 0x3F803F80, 0x3F803F80};
  constexpr float LOG2E = 1.44269504f;
  constexpr float SHIFT2 = -4.0f * LOG2E;

  f32x4 ot[4] = {};
  f32x4 lacc = {};

  for (int t = 0; t < 16; ++t) {
    int cur = t & 1;
    if (t + 1 < 16) stageKV(cur ^ 1, t + 1);
    unsigned char* kb_ = sm + 16384 + cur * 8192;
    unsigned char* vb_ = sm + 32768 + cur * 8192;

    f32x4 st[4] = {};
    __builtin_amdgcn_s_setprio(1);
    #pragma unroll
    for (int ks = 0; ks < 2; ++ks)
      #pragma unroll
      for (int kmt = 0; kmt < 4; ++kmt) {
        i32x4 ka = *(const i32x4*)(kb_ + ((ks * 4 + g4) * 64 + kmt * 16 + c15) * 16);
        mfma16(st[kmt], ka, qf[ks]);
      }
    __builtin_amdgcn_s_setprio(0);

    #pragma unroll
    for (int kmt = 0; kmt < 4; ++kmt) {
      float p0 = exp2f(__builtin_fmaf(st[kmt][0], LOG2E, SHIFT2));
      float p1 = exp2f(__builtin_fmaf(st[kmt][1], LOG2E, SHIFT2));
      float p2 = exp2f(__builtin_fmaf(st[kmt][2], LOG2E, SHIFT2));
      float p3 = exp2f(__builtin_fmaf(st[kmt][3], LOG2E, SHIFT2));
      int k0 = kmt * 16 + 4 * g4;
      uint2 ww;
      ww.x = cvtpk(p0, p1);
      ww.y = cvtpk(p2, p3);
      *(uint2*)(pw + ((k0 >> 3) * 16 + c15) * 16 + (k0 & 7) * 2) = ww;
    }

    i32x4 pb[2];
    #pragma unroll
    for (int ks = 0; ks < 2; ++ks)
      pb[ks] = *(const i32x4*)(pw + ((ks * 4 + g4) * 16 + c15) * 16);

    __builtin_amdgcn_s_setprio(1);
    #pragma unroll
    for (int ks = 0; ks < 2; ++ks) {
      #pragma unroll
      for (int dmt = 0; dmt < 4; ++dmt) {
        i32x4 va = *(const i32x4*)(vb_ + ((ks * 4 + g4) * 64 + dmt * 16 + c15) * 16);
        mfma16(ot[dmt], va, pb[ks]);
      }
      mfma16(lacc, ones, pb[ks]);
    }
    __builtin_amdgcn_s_setprio(0);
    __syncthreads();
  }

  const int b = bh / 12, h = bh % 12;
  float inv = 1.0f / lacc[0];
  int q = qt * 128 + wid * 16 + c15;
  size_t rowoff = ((size_t)(b * 1024 + q) * 12 + h) * 64;
  #pragma unroll
  for (int dmt = 0; dmt < 4; ++dmt) {
    int d0 = dmt * 16 + g4 * 4;
    uint2 uu;
    uu.x = cvtpk(ot[dmt][0] * inv, ot[dmt][1] * inv);
    uu.y = cvtpk(ot[dmt][2] * inv, ot[dmt][3] * inv);
    *(uint2*)(Ob + rowoff + d0) = uu;
  }
}

extern "C" void kernel_launch(void* const* d_in, const int* in_sizes, int n_in,
                              void* d_out, int out_size, void* d_ws, size_t ws_size,
                              hipStream_t stream) {
  const float* x    = (const float*)d_in[0];
  const float* qkvw = (const float*)d_in[1];
  const float* qkvb = (const float*)d_in[2];
  const float* outw = (const float*)d_in[3];
  const float* outb = (const float*)d_in[4];
  float* out = (float*)d_out;

  unsigned char* ws = (unsigned char*)d_ws;
  u16* xb  = (u16*)(ws);                          // 12.58 MB  [8192][768] bf16
  u16* wqb = (u16*)(ws + 12582912);               //  3.54 MB  [2304][768] bf16
  u16* wob = (u16*)(ws + 16121856);               //  1.18 MB  [768][768]  bf16
  u16* Qbf = (u16*)(ws + 17301504);               // 12.58 MB  [96][1024][64]
  u16* Kbf = (u16*)(ws + 29884416);               // 12.58 MB  [96][1024][64]
  u16* Vtb = (u16*)(ws + 42467328);               // 12.58 MB  [96][64][1024]
  u16* Ob  = xb;                                  // reuse x region (dead after gemm1)

  cvt3_f32_bf16<<<dim3(2048), dim3(256), 0, stream>>>(
      x, xb, 8192 * 768 / 4, qkvw, wqb, 2304 * 768 / 4, outw, wob, 768 * 768 / 4);

  gemm_bt<128, 128, 4, 4, 1><<<dim3(1152), dim3(256), 0, stream>>>(
      xb, wqb, 8192, 2304, qkvb, nullptr, Qbf, Kbf, Vtb);

  attn_fwd<<<dim3(768), dim3(512), 0, stream>>>(Qbf, Kbf, Vtb, Ob);

  gemm_bt<128, 64, 4, 2, 0><<<dim3(768), dim3(256), 0, stream>>>(
      Ob, wob, 8192, 768, outb, out, nullptr, nullptr, nullptr);
}

// Round 20
// 149.393 us; speedup vs baseline: 1.0194x; 1.0009x over previous
//
#include <hip/hip_runtime.h>
#include <stdint.h>

typedef float  f32x4 __attribute__((ext_vector_type(4)));
typedef int    i32x4 __attribute__((ext_vector_type(4)));
typedef short  bf16x8 __attribute__((ext_vector_type(8)));
typedef unsigned short u16;
typedef unsigned int   u32;

#define DEVINL __device__ __forceinline__

// fp32 -> bf16 RNE
DEVINL u16 f2bf(float f) {
  u32 u = __builtin_bit_cast(u32, f);
  u32 r = u + 0x7fffu + ((u >> 16) & 1u);
  return (u16)(r >> 16);
}

// packed fp32x2 -> bf16x2
DEVINL u32 cvtpk(float lo, float hi) {
  u32 r;
  asm("v_cvt_pk_bf16_f32 %0, %1, %2" : "=v"(r) : "v"(lo), "v"(hi));
  return r;
}

// D += A*B  (16x16x32 bf16 MFMA)
DEVINL void mfma16(f32x4& d, i32x4 a, i32x4 b) {
  d = __builtin_amdgcn_mfma_f32_16x16x32_bf16(
      __builtin_bit_cast(bf16x8, a), __builtin_bit_cast(bf16x8, b), d, 0, 0, 0);
}

// async global->LDS, 16B per lane; LDS dest linear per wave (base + lane*16)
#define GLD16(gp, lp) __builtin_amdgcn_global_load_lds( \
    (__attribute__((address_space(1))) void*)(gp), \
    (__attribute__((address_space(3))) void*)(lp), 16, 0, 0)

// one launch converting all three fp32 arrays to bf16
__global__ void cvt3_f32_bf16(const float* __restrict__ s0, u16* __restrict__ d0, int n0,
                              const float* __restrict__ s1, u16* __restrict__ d1, int n1,
                              const float* __restrict__ s2, u16* __restrict__ d2, int n2) {
  int i = blockIdx.x * blockDim.x + threadIdx.x;
  int stride = gridDim.x * blockDim.x;
  int nt = n0 + n1 + n2;
  for (; i < nt; i += stride) {
    const float* s; u16* d; int j = i;
    if (j < n0) { s = s0; d = d0; }
    else if ((j -= n0) < n1) { s = s1; d = d1; }
    else { j -= n1; s = s2; d = d2; }
    float4 v = ((const float4*)s)[j];
    ushort4 o;
    o.x = f2bf(v.x); o.y = f2bf(v.y); o.z = f2bf(v.z); o.w = f2bf(v.w);
    ((ushort4*)d)[j] = o;
  }
}

// ---------------------------------------------------------------------------
// C = A * B^T (+bias). BK=64 double-buffered 2-phase, N-major XCD walk
// (round-15/17 structure — measured best: gemm1 70.6-70.9us, FETCH 22.6MB).
// EPI==0: fp32 C + bias via LDS-retile.  EPI==1: QKV scatter via LDS-retile.
// ---------------------------------------------------------------------------
template<int BM, int BN, int FM, int FN, int EPI>
__global__ __launch_bounds__(256) void gemm_bt(
    const u16* __restrict__ A, const u16* __restrict__ Bw,
    int M, int N, const float* __restrict__ bias,
    float* __restrict__ Cf, u16* __restrict__ Qb, u16* __restrict__ Kb, u16* __restrict__ Vtb)
{
  constexpr int BK = 64;
  constexpr int K  = 768;
  constexpr int T  = K / BK;            // 12
  constexpr int ABYT = BM * BK * 2;
  constexpr int BBYT = BN * BK * 2;
  __shared__ __align__(16) unsigned char sm[2 * (ABYT + BBYT)];

  const int tid = threadIdx.x;
  const int l   = tid & 63;
  const int wid = tid >> 6;
  const int wm  = wid >> 1, wn = wid & 1;
  const int g4  = l >> 4;
  const int c15 = l & 15;

  const int ntiles = N / BN;
  const int mt_x = (M / BM) >> 3;       // m-tiles per XCD chunk
  const int xcd  = (int)blockIdx.x & 7;
  const int seq  = (int)blockIdx.x >> 3;
  const int mbase = (xcd * mt_x + (seq % mt_x)) * BM;
  const int nbase = (seq / mt_x) * BN;

  auto stage = [&](int buf, int kt) {
    unsigned char* ab = sm + buf * (ABYT + BBYT);
    unsigned char* bb = ab + ABYT;
    #pragma unroll
    for (int c = 0; c < BM / 32; ++c) {
      int ch = c * 256 + tid;
      int row = ch & (BM - 1), pl = ch / BM;
      GLD16(A + (size_t)(mbase + row) * K + kt * BK + pl * 8, ab + ch * 16);
    }
    #pragma unroll
    for (int c = 0; c < BN / 32; ++c) {
      int ch = c * 256 + tid;
      int row = ch & (BN - 1), pl = ch / BN;
      GLD16(Bw + (size_t)(nbase + row) * K + kt * BK + pl * 8, bb + ch * 16);
    }
  };

  f32x4 acc[FM][FN] = {};

  stage(0, 0);
  __syncthreads();

  for (int kt = 0; kt < T; ++kt) {
    int cur = kt & 1;
    if (kt + 1 < T) stage(cur ^ 1, kt + 1);
    unsigned char* ab = sm + cur * (ABYT + BBYT);
    unsigned char* bb = ab + ABYT;
    i32x4 af[FM][2], bf[FN][2];
    #pragma unroll
    for (int mt = 0; mt < FM; ++mt)
      #pragma unroll
      for (int ks = 0; ks < 2; ++ks) {
        int row = wm * (BM / 2) + mt * 16 + c15;
        af[mt][ks] = *(const i32x4*)(ab + ((ks * 4 + g4) * BM + row) * 16);
      }
    #pragma unroll
    for (int nt = 0; nt < FN; ++nt)
      #pragma unroll
      for (int ks = 0; ks < 2; ++ks) {
        int row = wn * (BN / 2) + nt * 16 + c15;
        bf[nt][ks] = *(const i32x4*)(bb + ((ks * 4 + g4) * BN + row) * 16);
      }
    __builtin_amdgcn_s_setprio(1);
    #pragma unroll
    for (int mt = 0; mt < FM; ++mt)
      #pragma unroll
      for (int nt = 0; nt < FN; ++nt)
        #pragma unroll
        for (int ks = 0; ks < 2; ++ks)
          mfma16(acc[mt][nt], af[mt][ks], bf[nt][ks]);
    __builtin_amdgcn_s_setprio(0);
    __syncthreads();
  }

  if constexpr (EPI == 0) {
    // ---- LDS-retile fp32 epilogue ----
    unsigned char* L = sm;
    #pragma unroll
    for (int nt = 0; nt < FN; ++nt) {
      int nrel = wn * (BN / 2) + nt * 16 + c15;
      float bv = bias[nbase + nrel];
      #pragma unroll
      for (int mt = 0; mt < FM; ++mt) {
        int m0 = wm * (BM / 2) + mt * 16 + g4 * 4;
        #pragma unroll
        for (int j = 0; j < 4; ++j) {
          int m = m0 + j;
          *(float*)(L + m * (BN * 4) + ((nrel * 4) ^ ((m & 7) << 4))) =
              acc[mt][nt][j] + bv;
        }
      }
    }
    __syncthreads();

    constexpr int CPR = BN / 4;
    #pragma unroll
    for (int k = 0; k < (BM * CPR) / 256; ++k) {
      int chunk = k * 256 + tid;
      int row = chunk / CPR, c = chunk % CPR;
      i32x4 vdat = *(const i32x4*)(L + row * (BN * 4) + ((c * 16) ^ ((row & 7) << 4)));
      *(i32x4*)(Cf + (size_t)(mbase + row) * N + nbase + c * 4) = vdat;
    }
  } else {
    // ---- LDS-retile epilogue (coalesced 128B+ runs) ----
    const int which = nbase / 768;
    const int hbase = (nbase - which * 768) >> 6;
    unsigned char* L = sm;

    if (which < 2) {
      const float sc = (which == 0) ? 0.125f : 1.0f;
      #pragma unroll
      for (int nt = 0; nt < FN; ++nt) {
        int nrel = wn * (BN / 2) + nt * 16 + c15;
        float bv = bias[nbase + nrel];
        #pragma unroll
        for (int mt = 0; mt < FM; ++mt) {
          int m0 = wm * (BM / 2) + mt * 16 + g4 * 4;
          #pragma unroll
          for (int j = 0; j < 4; ++j) {
            int m = m0 + j;
            *(u16*)(L + m * 256 + ((nrel * 2) ^ ((m & 7) << 4))) =
                f2bf((acc[mt][nt][j] + bv) * sc);
          }
        }
      }
    } else {
      #pragma unroll
      for (int nt = 0; nt < FN; ++nt) {
        int nrel = wn * (BN / 2) + nt * 16 + c15;
        float bv = bias[nbase + nrel];
        #pragma unroll
        for (int mt = 0; mt < FM; ++mt) {
          int m0 = wm * (BM / 2) + mt * 16 + g4 * 4;
          uint2 uu;
          uu.x = cvtpk(acc[mt][nt][0] + bv, acc[mt][nt][1] + bv);
          uu.y = cvtpk(acc[mt][nt][2] + bv, acc[mt][nt][3] + bv);
          *(uint2*)(L + nrel * 256 + ((m0 * 2) ^ ((nrel & 7) << 4))) = uu;
        }
      }
    }
    __syncthreads();

    const int b  = mbase >> 10;
    const int pb = mbase & 1023;
    #pragma unroll
    for (int k = 0; k < 8; ++k) {
      int chunk = k * 256 + tid;
      int row = chunk >> 4, c = chunk & 15;
      i32x4 vdat = *(const i32x4*)(L + row * 256 + ((c * 16) ^ ((row & 7) << 4)));
      if (which < 2) {
        int h = hbase + (c >> 3), d0 = (c & 7) * 8;
        int bh = b * 12 + h;
        u16* base = (which == 0) ? Qb : Kb;
        *(i32x4*)(base + ((size_t)bh * 1024 + pb + row) * 64 + d0) = vdat;
      } else {
        int h = hbase + (row >> 6), d = row & 63;
        int bh = b * 12 + h;
        *(i32x4*)(Vtb + ((size_t)bh * 64 + d) * 1024 + pb + c * 8) = vdat;
      }
    }
  }
}

// ---------------------------------------------------------------------------
// Flash attention — 8 waves x 16 q-rows (512 thr), fixed-shift softmax.
// __launch_bounds__(512, 6): cap VGPR at 85 so 3 blocks/CU (24 waves) fit —
// LDS allows 3, but >85 VGPR silently caps at 2 blocks (16 waves). attn is
// the TLP-responsive kernel (r17: +waves = -13.8us), so unlock the 3rd block.
// ---------------------------------------------------------------------------
__global__ __launch_bounds__(512, 6) void attn_fwd(
    const u16* __restrict__ Qb, const u16* __restrict__ Kb,
    const u16* __restrict__ Vtb, u16* __restrict__ Ob)
{
  __shared__ __align__(16) unsigned char sm[16384 + 4 * 8192];
  const int tid = threadIdx.x;
  const int l = tid & 63, wid = tid >> 6;
  const int g4 = l >> 4, c15 = l & 15;
  const int bid = blockIdx.x;
  const int bh = bid % 96, qt = bid / 96;

  const size_t bhoff = (size_t)bh * (1024 * 64);
  const u16* Qg = Qb + bhoff + (size_t)qt * 128 * 64;
  const u16* Kg = Kb + bhoff;
  const u16* Vg = Vtb + bhoff;

  #pragma unroll
  for (int c = 0; c < 2; ++c) {
    int ch = c * 512 + tid;
    int row = ch & 127, pl = ch >> 7;
    GLD16(Qg + (size_t)row * 64 + pl * 8, sm + ch * 16);
  }

  auto stageKV = [&](int buf, int t) {
    unsigned char* kb_ = sm + 16384 + buf * 8192;
    unsigned char* vb_ = sm + 32768 + buf * 8192;
    int row = tid & 63, pl = (tid >> 6) & 7;
    GLD16(Kg + (size_t)(t * 64 + row) * 64 + pl * 8, kb_ + tid * 16);
    GLD16(Vg + (size_t)row * 1024 + t * 64 + pl * 8, vb_ + tid * 16);
  };

  stageKV(0, 0);
  __syncthreads();

  i32x4 qf[2];
  #pragma unroll
  for (int ks = 0; ks < 2; ++ks) {
    int row = wid * 16 + c15;
    qf[ks] = *(const i32x4*)(sm + ((ks * 4 + g4) * 128 + row) * 16);
  }
  __syncthreads();

  unsigned char* pw = sm + wid * 2048;

  const i32x4 ones = {0x3F803F80, 0x3F803F80, 0x3F803F80, 0x3F803F80};
  constexpr float LOG2E = 1.44269504f;
  constexpr float SHIFT2 = -4.0f * LOG2E;

  f32x4 ot[4] = {};
  f32x4 lacc = {};

  for (int t = 0; t < 16; ++t) {
    int cur = t & 1;
    if (t + 1 < 16) stageKV(cur ^ 1, t + 1);
    unsigned char* kb_ = sm + 16384 + cur * 8192;
    unsigned char* vb_ = sm + 32768 + cur * 8192;

    f32x4 st[4] = {};
    __builtin_amdgcn_s_setprio(1);
    #pragma unroll
    for (int ks = 0; ks < 2; ++ks)
      #pragma unroll
      for (int kmt = 0; kmt < 4; ++kmt) {
        i32x4 ka = *(const i32x4*)(kb_ + ((ks * 4 + g4) * 64 + kmt * 16 + c15) * 16);
        mfma16(st[kmt], ka, qf[ks]);
      }
    __builtin_amdgcn_s_setprio(0);

    #pragma unroll
    for (int kmt = 0; kmt < 4; ++kmt) {
      float p0 = exp2f(__builtin_fmaf(st[kmt][0], LOG2E, SHIFT2));
      float p1 = exp2f(__builtin_fmaf(st[kmt][1], LOG2E, SHIFT2));
      float p2 = exp2f(__builtin_fmaf(st[kmt][2], LOG2E, SHIFT2));
      float p3 = exp2f(__builtin_fmaf(st[kmt][3], LOG2E, SHIFT2));
      int k0 = kmt * 16 + 4 * g4;
      uint2 ww;
      ww.x = cvtpk(p0, p1);
      ww.y = cvtpk(p2, p3);
      *(uint2*)(pw + ((k0 >> 3) * 16 + c15) * 16 + (k0 & 7) * 2) = ww;
    }

    i32x4 pb[2];
    #pragma unroll
    for (int ks = 0; ks < 2; ++ks)
      pb[ks] = *(const i32x4*)(pw + ((ks * 4 + g4) * 16 + c15) * 16);

    __builtin_amdgcn_s_setprio(1);
    #pragma unroll
    for (int ks = 0; ks < 2; ++ks) {
      #pragma unroll
      for (int dmt = 0; dmt < 4; ++dmt) {
        i32x4 va = *(const i32x4*)(vb_ + ((ks * 4 + g4) * 64 + dmt * 16 + c15) * 16);
        mfma16(ot[dmt], va, pb[ks]);
      }
      mfma16(lacc, ones, pb[ks]);
    }
    __builtin_amdgcn_s_setprio(0);
    __syncthreads();
  }

  const int b = bh / 12, h = bh % 12;
  float inv = 1.0f / lacc[0];
  int q = qt * 128 + wid * 16 + c15;
  size_t rowoff = ((size_t)(b * 1024 + q) * 12 + h) * 64;
  #pragma unroll
  for (int dmt = 0; dmt < 4; ++dmt) {
    int d0 = dmt * 16 + g4 * 4;
    uint2 uu;
    uu.x = cvtpk(ot[dmt][0] * inv, ot[dmt][1] * inv);
    uu.y = cvtpk(ot[dmt][2] * inv, ot[dmt][3] * inv);
    *(uint2*)(Ob + rowoff + d0) = uu;
  }
}

extern "C" void kernel_launch(void* const* d_in, const int* in_sizes, int n_in,
                              void* d_out, int out_size, void* d_ws, size_t ws_size,
                              hipStream_t stream) {
  const float* x    = (const float*)d_in[0];
  const float* qkvw = (const float*)d_in[1];
  const float* qkvb = (const float*)d_in[2];
  const float* outw = (const float*)d_in[3];
  const float* outb = (const float*)d_in[4];
  float* out = (float*)d_out;

  unsigned char* ws = (unsigned char*)d_ws;
  u16* xb  = (u16*)(ws);                          // 12.58 MB  [8192][768] bf16
  u16* wqb = (u16*)(ws + 12582912);               //  3.54 MB  [2304][768] bf16
  u16* wob = (u16*)(ws + 16121856);               //  1.18 MB  [768][768]  bf16
  u16* Qbf = (u16*)(ws + 17301504);               // 12.58 MB  [96][1024][64]
  u16* Kbf = (u16*)(ws + 29884416);               // 12.58 MB  [96][1024][64]
  u16* Vtb = (u16*)(ws + 42467328);               // 12.58 MB  [96][64][1024]
  u16* Ob  = xb;                                  // reuse x region (dead after gemm1)

  cvt3_f32_bf16<<<dim3(2048), dim3(256), 0, stream>>>(
      x, xb, 8192 * 768 / 4, qkvw, wqb, 2304 * 768 / 4, outw, wob, 768 * 768 / 4);

  gemm_bt<128, 128, 4, 4, 1><<<dim3(1152), dim3(256), 0, stream>>>(
      xb, wqb, 8192, 2304, qkvb, nullptr, Qbf, Kbf, Vtb);

  attn_fwd<<<dim3(768), dim3(512), 0, stream>>>(Qbf, Kbf, Vtb, Ob);

  gemm_bt<128, 64, 4, 2, 0><<<dim3(768), dim3(256), 0, stream>>>(
      Ob, wob, 8192, 768, outb, out, nullptr, nullptr, nullptr);
}